// Round 4
// baseline (445.228 us; speedup 1.0000x reference)
//
#include <hip/hip_runtime.h>
#include <math.h>

#define N_NODES 50000
#define N_REL   1000
#define N_EDGES 600000
#define D       128
#define OUT_COLS 384   // 3*D concat output row stride

#define FEAT0_BLOCKS  ((N_NODES * (D / 4) + 255) / 256)   // 6250
#define RELN_BLOCKS   ((N_REL + 3) / 4)                   // 250
#define ROWPTR_BLOCKS ((N_NODES + 1 + 255) / 256)         // 196
#define SETUP_BLOCKS  (FEAT0_BLOCKS + RELN_BLOCKS + ROWPTR_BLOCKS + 1)

__device__ __forceinline__ float wave_reduce_sum64(float v) {
#pragma unroll
    for (int m = 1; m < 64; m <<= 1) v += __shfl_xor(v, m, 64);
    return v;
}

__device__ __forceinline__ float group_reduce_sum16(float v) {
#pragma unroll
    for (int m = 1; m < 16; m <<= 1) v += __shfl_xor(v, m, 64);
    return v;
}

__device__ __forceinline__ float tanh_fast(float x) {
    float cx = fminf(fmaxf(x, -20.0f), 20.0f);
    float e = __expf(2.0f * cx);
    return __fdividef(e - 1.0f, e + 1.0f);
}

__device__ __forceinline__ float sigmoid_fast(float x) {
    return __fdividef(1.0f, 1.0f + __expf(-x));
}

// --- fused setup: feats0 tanh + compact copy | relnorm + exp tables | rowptr | wcomb ---
__global__ __launch_bounds__(256) void k_setup(
        const float* __restrict__ features, const float* __restrict__ rel_emb,
        const float* __restrict__ attn_k, const float* __restrict__ attn_w,
        const float* __restrict__ gate_w, const int* __restrict__ dstv,
        float* __restrict__ out0, float* __restrict__ out1, float* __restrict__ fc0,
        float* __restrict__ rel_norm, float* __restrict__ er0, float* __restrict__ er1,
        float* __restrict__ wcomb, int* __restrict__ row_ptr) {
    int bid = blockIdx.x, tid = threadIdx.x;
    if (bid < FEAT0_BLOCKS) {
        int i = bid * 256 + tid;
        if (i >= N_NODES * (D / 4)) return;
        int n = i >> 5, q = i & 31;
        float4 f = *(const float4*)(features + (size_t)n * D + 4 * q);
        f.x = tanh_fast(f.x); f.y = tanh_fast(f.y);
        f.z = tanh_fast(f.z); f.w = tanh_fast(f.w);
        *(float4*)(out0 + (size_t)n * OUT_COLS + 4 * q) = f;
        *(float4*)(out1 + (size_t)n * OUT_COLS + 4 * q) = f;
        *(float4*)(fc0 + (size_t)n * D + 4 * q) = f;
    } else if (bid < FEAT0_BLOCKS + RELN_BLOCKS) {
        int wid  = (bid - FEAT0_BLOCKS) * 4 + (tid >> 6);
        int lane = tid & 63;
        if (wid >= N_REL) return;
        float2 v = *(const float2*)(rel_emb + (size_t)wid * D + 2 * lane);
        float sq = wave_reduce_sum64(v.x * v.x + v.y * v.y);
        float inv = 1.0f / fmaxf(sqrtf(sq), 1e-12f);
        float2 u = make_float2(v.x * inv, v.y * inv);
        *(float2*)(rel_norm + (size_t)wid * D + 2 * lane) = u;
        float2 k0 = *(const float2*)(attn_k + 2 * lane);
        float2 k1 = *(const float2*)(attn_k + D + 2 * lane);
        float d0 = wave_reduce_sum64(u.x * k0.x + u.y * k0.y);
        float d1 = wave_reduce_sum64(u.x * k1.x + u.y * k1.y);
        if (lane == 0) { er0[wid] = __expf(d0); er1[wid] = __expf(d1); }
    } else if (bid < FEAT0_BLOCKS + RELN_BLOCKS + ROWPTR_BLOCKS) {
        int n = (bid - FEAT0_BLOCKS - RELN_BLOCKS) * 256 + tid;
        if (n > N_NODES) return;
        int lo = 0, hi = N_EDGES;
        while (lo < hi) {
            int mid = (lo + hi) >> 1;
            if (dstv[mid] < n) lo = mid + 1; else hi = mid;
        }
        row_ptr[n] = lo;
    } else {
        int j = tid;
        if (j >= D) return;
        wcomb[j]         = attn_w[j] + attn_w[2 * D + j];       // wA_dst
        wcomb[D + j]     = attn_w[D + j] - attn_w[2 * D + j];   // wA_src
        wcomb[2 * D + j] = gate_w[j] + gate_w[2 * D + j];       // wG_dst
        wcomb[3 * D + j] = gate_w[D + j] - gate_w[2 * D + j];   // wG_src
    }
}

// --- structural pass: one wave per node, 16-lane row groups (4 edges/iter) ---
__global__ __launch_bounds__(256) void k_struct(
        const float* __restrict__ finC,   // compact input feats, stride D
        float* __restrict__ foutC,        // compact output feats, stride D
        float* __restrict__ foutS,        // out0 column slice, stride OUT_COLS
        const int* __restrict__ row_ptr, const int* __restrict__ srcv,
        const int* __restrict__ relv, const float* __restrict__ rval,
        const float* __restrict__ er,
        const float* __restrict__ rel_norm, const float* __restrict__ wcomb,
        float* __restrict__ node_Z, float* __restrict__ proj) {
    int n    = (blockIdx.x * blockDim.x + threadIdx.x) >> 6;
    int lane = threadIdx.x & 63;
    int g = lane >> 4, l = lane & 15;
    if (n >= N_NODES) return;
    int beg = row_ptr[n], end = row_ptr[n + 1];

    float4 acc0 = make_float4(0.f, 0.f, 0.f, 0.f);
    float4 acc1 = make_float4(0.f, 0.f, 0.f, 0.f);
    float Zp = 0.f;

    for (int cs = beg; cs < end; cs += 64) {
        int cnt = min(64, end - cs);
        int my_s = 0, my_r = -1; float my_w = 0.f;
        if (lane < cnt) {
            int e = cs + lane;
            my_s = srcv[e];
            int rr = relv[e];
            bool pos = rval[e] > 0.0f;   // r_val==0 -> tri_rel is zero vector
            my_r = pos ? rr : -1;
            my_w = pos ? er[rr] : 1.0f;  // exp(structural logit); exp(0)=1 degenerate
            Zp += my_w;
        }
        int nit = (cnt + 3) >> 2;
        for (int i = 0; i < nit; ++i) {
            int sl = (i << 2) | g;
            int   s = __shfl(my_s, sl, 64);
            int   r = __shfl(my_r, sl, 64);
            float w = __shfl(my_w, sl, 64);
            const float* xp = finC + (size_t)s * D + 8 * l;
            float4 x0 = *(const float4*)xp;
            float4 x1 = *(const float4*)(xp + 4);
            int rr = r < 0 ? 0 : r;
            const float* up = rel_norm + (size_t)rr * D + 8 * l;
            float4 u0 = *(const float4*)up;
            float4 u1 = *(const float4*)(up + 4);
            float p = x0.x*u0.x + x0.y*u0.y + x0.z*u0.z + x0.w*u0.w
                    + x1.x*u1.x + x1.y*u1.y + x1.z*u1.z + x1.w*u1.w;
            p = group_reduce_sum16(p);
            float wc = (r >= 0) ? 2.0f * w * p : 0.0f;
            acc0.x += w * x0.x - wc * u0.x;
            acc0.y += w * x0.y - wc * u0.y;
            acc0.z += w * x0.z - wc * u0.z;
            acc0.w += w * x0.w - wc * u0.w;
            acc1.x += w * x1.x - wc * u1.x;
            acc1.y += w * x1.y - wc * u1.y;
            acc1.z += w * x1.z - wc * u1.z;
            acc1.w += w * x1.w - wc * u1.w;
        }
    }
    float Z = wave_reduce_sum64(Zp);
#pragma unroll
    for (int m = 16; m < 64; m <<= 1) {
        acc0.x += __shfl_xor(acc0.x, m, 64);
        acc0.y += __shfl_xor(acc0.y, m, 64);
        acc0.z += __shfl_xor(acc0.z, m, 64);
        acc0.w += __shfl_xor(acc0.w, m, 64);
        acc1.x += __shfl_xor(acc1.x, m, 64);
        acc1.y += __shfl_xor(acc1.y, m, 64);
        acc1.z += __shfl_xor(acc1.z, m, 64);
        acc1.w += __shfl_xor(acc1.w, m, 64);
    }
    float invZ = (end > beg) ? (1.0f / Z) : 0.0f;
    float4 o0, o1;
    o0.x = tanh_fast(acc0.x * invZ); o0.y = tanh_fast(acc0.y * invZ);
    o0.z = tanh_fast(acc0.z * invZ); o0.w = tanh_fast(acc0.w * invZ);
    o1.x = tanh_fast(acc1.x * invZ); o1.y = tanh_fast(acc1.y * invZ);
    o1.z = tanh_fast(acc1.z * invZ); o1.w = tanh_fast(acc1.w * invZ);

    // per-node projections onto the 4 combined semantic weight vectors
    float pr[4];
#pragma unroll
    for (int k = 0; k < 4; ++k) {
        const float* wp = wcomb + k * D + 8 * l;
        float4 w0 = *(const float4*)wp;
        float4 w1 = *(const float4*)(wp + 4);
        float p = o0.x*w0.x + o0.y*w0.y + o0.z*w0.z + o0.w*w0.w
                + o1.x*w1.x + o1.y*w1.y + o1.z*w1.z + o1.w*w1.w;
        pr[k] = group_reduce_sum16(p);
    }
    if (lane == 0) {
        node_Z[n] = Z;
        *(float4*)(proj + 4 * (size_t)n) = make_float4(pr[0], pr[1], pr[2], pr[3]);
    }
    if (g == 0) {
        float* op = foutS + (size_t)n * OUT_COLS + 8 * l;
        *(float4*)op = o0;
        *(float4*)(op + 4) = o1;
        float* cp = foutC + (size_t)n * D + 8 * l;
        *(float4*)cp = o0;
        *(float4*)(cp + 4) = o1;
    }
}

// --- semantic pass: per-edge weights from per-node projections; no per-edge dots ---
__global__ __launch_bounds__(256) void k_sem(
        const float* __restrict__ featsC, // compact updated feats, stride D
        float* __restrict__ oput,         // out1 column slice, stride OUT_COLS
        const int* __restrict__ row_ptr, const int* __restrict__ srcv,
        const int* __restrict__ relv, const float* __restrict__ rval,
        const float* __restrict__ er, const float* __restrict__ node_Z,
        const float* __restrict__ proj,
        const float* __restrict__ attn_b, const float* __restrict__ gate_b) {
    int n    = (blockIdx.x * blockDim.x + threadIdx.x) >> 6;
    int lane = threadIdx.x & 63;
    int g = lane >> 4, l = lane & 15;
    if (n >= N_NODES) return;
    int beg = row_ptr[n], end = row_ptr[n + 1];

    float4 pn = *(const float4*)(proj + 4 * (size_t)n);
    float ca = pn.x + attn_b[0];
    float cg = pn.z + gate_b[0];
    float invZ = (end > beg) ? (1.0f / node_Z[n]) : 0.0f;

    float4 acc0 = make_float4(0.f, 0.f, 0.f, 0.f);
    float4 acc1 = make_float4(0.f, 0.f, 0.f, 0.f);
    float Zs = 0.f;

    for (int cs = beg; cs < end; cs += 64) {
        int cnt = min(64, end - cs);
        int my_s = 0; float my_wt = 0.f;
        if (lane < cnt) {
            int e = cs + lane;
            my_s = srcv[e];
            int rr = relv[e];
            bool pos = rval[e] > 0.0f;
            float sw = (pos ? er[rr] : 1.0f) * invZ;       // att_struct
            float4 ps = *(const float4*)(proj + 4 * (size_t)my_s);
            float as = fmaxf(sigmoid_fast(ca + ps.y), 1e-4f);
            float gt = sigmoid_fast(cg + ps.w);
            my_wt = __expf(gt * as + (1.0f - gt) * sw);    // logit in (0,1], exp-safe
            Zs += my_wt;
        }
        int nit = (cnt + 3) >> 2;
        for (int i = 0; i < nit; ++i) {
            int sl = (i << 2) | g;
            int   s  = __shfl(my_s, sl, 64);
            float wt = __shfl(my_wt, sl, 64);
            const float* xp = featsC + (size_t)s * D + 8 * l;
            float4 x0 = *(const float4*)xp;
            float4 x1 = *(const float4*)(xp + 4);
            acc0.x += wt * x0.x; acc0.y += wt * x0.y;
            acc0.z += wt * x0.z; acc0.w += wt * x0.w;
            acc1.x += wt * x1.x; acc1.y += wt * x1.y;
            acc1.z += wt * x1.z; acc1.w += wt * x1.w;
        }
    }
    Zs = wave_reduce_sum64(Zs);
#pragma unroll
    for (int m = 16; m < 64; m <<= 1) {
        acc0.x += __shfl_xor(acc0.x, m, 64);
        acc0.y += __shfl_xor(acc0.y, m, 64);
        acc0.z += __shfl_xor(acc0.z, m, 64);
        acc0.w += __shfl_xor(acc0.w, m, 64);
        acc1.x += __shfl_xor(acc1.x, m, 64);
        acc1.y += __shfl_xor(acc1.y, m, 64);
        acc1.z += __shfl_xor(acc1.z, m, 64);
        acc1.w += __shfl_xor(acc1.w, m, 64);
    }
    if (g == 0) {
        float invZs = (end > beg) ? (1.0f / Zs) : 0.0f;
        float sc    = (end > beg) ? 1.0f : 0.0f;
        const float* sp = featsC + (size_t)n * D + 8 * l;
        float4 s0 = *(const float4*)sp;
        float4 s1 = *(const float4*)(sp + 4);
        float4 o0, o1;
        // out = tanh(se - (Σ wt·x)/Σ wt)
        o0.x = tanh_fast(sc * (s0.x - acc0.x * invZs));
        o0.y = tanh_fast(sc * (s0.y - acc0.y * invZs));
        o0.z = tanh_fast(sc * (s0.z - acc0.z * invZs));
        o0.w = tanh_fast(sc * (s0.w - acc0.w * invZs));
        o1.x = tanh_fast(sc * (s1.x - acc1.x * invZs));
        o1.y = tanh_fast(sc * (s1.y - acc1.y * invZs));
        o1.z = tanh_fast(sc * (s1.z - acc1.z * invZs));
        o1.w = tanh_fast(sc * (s1.w - acc1.w * invZs));
        float* op = oput + (size_t)n * OUT_COLS + 8 * l;
        *(float4*)op = o0;
        *(float4*)(op + 4) = o1;
    }
}

extern "C" void kernel_launch(void* const* d_in, const int* in_sizes, int n_in,
                              void* d_out, int out_size, void* d_ws, size_t ws_size,
                              hipStream_t stream) {
    const float* features = (const float*)d_in[0];
    const float* rel_emb  = (const float*)d_in[1];
    const int*   adj      = (const int*)d_in[2];   // [0:E]=dst (sorted), [E:2E]=src
    const int*   r_index  = (const int*)d_in[3];   // [0:E]=arange (identity), [E:2E]=rel
    const float* r_val    = (const float*)d_in[4];
    const float* attn_w   = (const float*)d_in[5];
    const float* attn_b   = (const float*)d_in[6];
    const float* gate_w   = (const float*)d_in[7];
    const float* gate_b   = (const float*)d_in[8];
    const float* attn_k   = (const float*)d_in[9]; // (2,128,1)

    float* out0 = (float*)d_out;                          // N x 384 (outs_c)
    float* out1 = out0 + (size_t)N_NODES * OUT_COLS;      // N x 384 (outs_s)

    // workspace carve-up (~78.5 MB)
    float* rel_norm = (float*)d_ws;                       // N_REL*D
    float* er0      = rel_norm + (size_t)N_REL * D;       // N_REL
    float* er1      = er0 + N_REL;                        // N_REL
    float* wcomb    = er1 + N_REL;                        // 4*D
    float* proj     = wcomb + 4 * D;                      // 4*N_NODES
    float* node_Z   = proj + 4 * (size_t)N_NODES;         // N_NODES
    int*   row_ptr  = (int*)(node_Z + N_NODES);           // N_NODES+1 (pad to +4)
    float* fc0      = (float*)(row_ptr + N_NODES + 4);    // N_NODES*D
    float* fc1      = fc0 + (size_t)N_NODES * D;          // N_NODES*D
    float* fc2      = fc1 + (size_t)N_NODES * D;          // N_NODES*D

    const int* dstv = adj;
    const int* srcv = adj + N_EDGES;
    const int* relv = r_index + N_EDGES;

    k_setup<<<SETUP_BLOCKS, 256, 0, stream>>>(
        features, rel_emb, attn_k, attn_w, gate_w, dstv,
        out0, out1, fc0, rel_norm, er0, er1, wcomb, row_ptr);

    const float* fcin[3] = {fc0, fc1, fc2};
    for (int l = 0; l < 2; ++l) {
        const float* er = l ? er1 : er0;
        k_struct<<<(N_NODES + 3) / 4, 256, 0, stream>>>(
            fcin[l], (float*)fcin[l + 1], out0 + (size_t)(l + 1) * D,
            row_ptr, srcv, relv, r_val, er, rel_norm, wcomb, node_Z, proj);
        k_sem<<<(N_NODES + 3) / 4, 256, 0, stream>>>(
            fcin[l + 1], out1 + (size_t)(l + 1) * D,
            row_ptr, srcv, relv, r_val, er, node_Z, proj, attn_b, gate_b);
    }
}

// Round 5
// 376.918 us; speedup vs baseline: 1.1812x; 1.1812x over previous
//
#include <hip/hip_runtime.h>
#include <math.h>

#define N_NODES 50000
#define N_REL   1000
#define N_EDGES 600000
#define D       128
#define OUT_COLS 384   // 3*D concat output row stride

typedef unsigned short ushortT;

#define FEAT0_BLOCKS  ((N_NODES * (D / 4) + 255) / 256)   // 6250
#define RELN_BLOCKS   ((N_REL + 3) / 4)                   // 250
#define ROWPTR_BLOCKS ((N_NODES + 1 + 255) / 256)         // 196
#define SETUP_BLOCKS  (FEAT0_BLOCKS + RELN_BLOCKS + ROWPTR_BLOCKS + 1)

__device__ __forceinline__ float wave_reduce_sum64(float v) {
#pragma unroll
    for (int m = 1; m < 64; m <<= 1) v += __shfl_xor(v, m, 64);
    return v;
}

// --- DPP 16-lane sum: 4 VALU ops, result on all 16 lanes of each row ---
template <int CTRL>
__device__ __forceinline__ float dpp_add_(float v) {
    int t = __builtin_amdgcn_update_dpp(0, __float_as_int(v), CTRL, 0xf, 0xf, true);
    return v + __int_as_float(t);
}
__device__ __forceinline__ float group_sum16(float v) {
    v = dpp_add_<0xB1>(v);    // quad_perm [1,0,3,2]  (xor 1)
    v = dpp_add_<0x4E>(v);    // quad_perm [2,3,0,1]  (xor 2)
    v = dpp_add_<0x141>(v);   // row_half_mirror      (combine quads)
    v = dpp_add_<0x140>(v);   // row_mirror           (combine halves)
    return v;
}

__device__ __forceinline__ float tanh_fast(float x) {
    float cx = fminf(fmaxf(x, -20.0f), 20.0f);
    float e = __expf(2.0f * cx);
    return __fdividef(e - 1.0f, e + 1.0f);
}
__device__ __forceinline__ float sigmoid_fast(float x) {
    return __fdividef(1.0f, 1.0f + __expf(-x));
}

// --- bf16 helpers (gather buffers only; all accumulation stays f32) ---
__device__ __forceinline__ void bf16x8_to_f32(uint4 q, float4& a, float4& b) {
    a.x = __int_as_float((int)(q.x << 16));
    a.y = __int_as_float((int)(q.x & 0xffff0000u));
    a.z = __int_as_float((int)(q.y << 16));
    a.w = __int_as_float((int)(q.y & 0xffff0000u));
    b.x = __int_as_float((int)(q.z << 16));
    b.y = __int_as_float((int)(q.z & 0xffff0000u));
    b.z = __int_as_float((int)(q.w << 16));
    b.w = __int_as_float((int)(q.w & 0xffff0000u));
}
__device__ __forceinline__ unsigned pack_bf16x2(float lo, float hi) {
    unsigned a = __float_as_uint(lo), b = __float_as_uint(hi);
    a = (a + 0x7fffu + ((a >> 16) & 1u)) >> 16;          // RNE (inputs finite)
    b = (b + 0x7fffu + ((b >> 16) & 1u));
    return (a & 0xffffu) | (b & 0xffff0000u);
}

// --- fused setup: feats0 tanh (+bf16 compact copy) | relnorm+exp | rowptr | wcomb ---
__global__ __launch_bounds__(256) void k_setup(
        const float* __restrict__ features, const float* __restrict__ rel_emb,
        const float* __restrict__ attn_k, const float* __restrict__ attn_w,
        const float* __restrict__ gate_w, const int* __restrict__ dstv,
        float* __restrict__ out0, float* __restrict__ out1, ushortT* __restrict__ fc0,
        float* __restrict__ rel_norm, float* __restrict__ er0, float* __restrict__ er1,
        float* __restrict__ wcomb, int* __restrict__ row_ptr) {
    int bid = blockIdx.x, tid = threadIdx.x;
    if (bid < FEAT0_BLOCKS) {
        int i = bid * 256 + tid;
        if (i >= N_NODES * (D / 4)) return;
        int n = i >> 5, q = i & 31;
        float4 f = *(const float4*)(features + (size_t)n * D + 4 * q);
        f.x = tanh_fast(f.x); f.y = tanh_fast(f.y);
        f.z = tanh_fast(f.z); f.w = tanh_fast(f.w);
        *(float4*)(out0 + (size_t)n * OUT_COLS + 4 * q) = f;
        *(float4*)(out1 + (size_t)n * OUT_COLS + 4 * q) = f;
        uint2 p = make_uint2(pack_bf16x2(f.x, f.y), pack_bf16x2(f.z, f.w));
        *((uint2*)(fc0 + (size_t)n * D) + q) = p;
    } else if (bid < FEAT0_BLOCKS + RELN_BLOCKS) {
        int wid  = (bid - FEAT0_BLOCKS) * 4 + (tid >> 6);
        int lane = tid & 63;
        if (wid >= N_REL) return;
        float2 v = *(const float2*)(rel_emb + (size_t)wid * D + 2 * lane);
        float sq = wave_reduce_sum64(v.x * v.x + v.y * v.y);
        float inv = 1.0f / fmaxf(sqrtf(sq), 1e-12f);
        float2 u = make_float2(v.x * inv, v.y * inv);
        *(float2*)(rel_norm + (size_t)wid * D + 2 * lane) = u;
        float2 k0 = *(const float2*)(attn_k + 2 * lane);
        float2 k1 = *(const float2*)(attn_k + D + 2 * lane);
        float d0 = wave_reduce_sum64(u.x * k0.x + u.y * k0.y);
        float d1 = wave_reduce_sum64(u.x * k1.x + u.y * k1.y);
        if (lane == 0) { er0[wid] = __expf(d0); er1[wid] = __expf(d1); }
    } else if (bid < FEAT0_BLOCKS + RELN_BLOCKS + ROWPTR_BLOCKS) {
        int n = (bid - FEAT0_BLOCKS - RELN_BLOCKS) * 256 + tid;
        if (n > N_NODES) return;
        int lo = 0, hi = N_EDGES;
        while (lo < hi) {
            int mid = (lo + hi) >> 1;
            if (dstv[mid] < n) lo = mid + 1; else hi = mid;
        }
        row_ptr[n] = lo;
    } else {
        int j = tid;
        if (j >= D) return;
        wcomb[j]         = attn_w[j] + attn_w[2 * D + j];       // wA_dst
        wcomb[D + j]     = attn_w[D + j] - attn_w[2 * D + j];   // wA_src
        wcomb[2 * D + j] = gate_w[j] + gate_w[2 * D + j];       // wG_dst
        wcomb[3 * D + j] = gate_w[D + j] - gate_w[2 * D + j];   // wG_src
    }
}

// --- structural pass: one wave per node, 16-lane groups, pipelined bf16 gathers ---
__global__ __launch_bounds__(256) void k_struct(
        const ushortT* __restrict__ finC,  // bf16 compact input feats, stride D
        ushortT* __restrict__ foutC,       // bf16 compact output feats, stride D
        float* __restrict__ foutS,         // out0 column slice (f32, stride OUT_COLS)
        const int* __restrict__ row_ptr, const int* __restrict__ srcv,
        const int* __restrict__ relv, const float* __restrict__ rval,
        const float* __restrict__ er,
        const float* __restrict__ rel_norm, const float* __restrict__ wcomb,
        float* __restrict__ node_Z, float* __restrict__ proj) {
    int n    = (blockIdx.x * blockDim.x + threadIdx.x) >> 6;
    int lane = threadIdx.x & 63;
    int g = lane >> 4, l = lane & 15;
    if (n >= N_NODES) return;
    int beg = row_ptr[n], end = row_ptr[n + 1];

    float4 acc0 = make_float4(0.f, 0.f, 0.f, 0.f);
    float4 acc1 = make_float4(0.f, 0.f, 0.f, 0.f);
    float Zp = 0.f;

    for (int cs = beg; cs < end; cs += 64) {
        int cnt = min(64, end - cs);
        int my_s = 0, my_r = -1; float my_w = 0.f;
        if (lane < cnt) {
            int e = cs + lane;
            my_s = srcv[e];
            int rr = relv[e];
            bool pos = rval[e] > 0.0f;   // r_val==0 -> tri_rel is zero vector
            my_r = pos ? rr : -1;
            my_w = pos ? er[rr] : 1.0f;
            Zp += my_w;
        }
        int nit = (cnt + 3) >> 2;
        // software pipeline: prefetch edge for iteration 0
        int   s = __shfl(my_s, g, 64);
        int   r = __shfl(my_r, g, 64);
        float w = __shfl(my_w, g, 64);
        uint4 xq = *((const uint4*)(finC + (size_t)s * D) + l);
        {
            int rr = r < 0 ? 0 : r;
            const float* up = rel_norm + (size_t)rr * D + 8 * l;
            float4 u0 = *(const float4*)up;
            float4 u1 = *(const float4*)(up + 4);
            for (int i = 0; i < nit; ++i) {
                int s_c = s; int r_c = r; float w_c = w;
                uint4 xq_c = xq; float4 u0_c = u0, u1_c = u1;
                (void)s_c;
                if (i + 1 < nit) {   // issue next iteration's gathers early
                    int sl2 = ((i + 1) << 2) | g;
                    s = __shfl(my_s, sl2, 64);
                    r = __shfl(my_r, sl2, 64);
                    w = __shfl(my_w, sl2, 64);
                    xq = *((const uint4*)(finC + (size_t)s * D) + l);
                    int rr2 = r < 0 ? 0 : r;
                    const float* up2 = rel_norm + (size_t)rr2 * D + 8 * l;
                    u0 = *(const float4*)up2;
                    u1 = *(const float4*)(up2 + 4);
                }
                float4 x0, x1;
                bf16x8_to_f32(xq_c, x0, x1);
                float p = x0.x*u0_c.x + x0.y*u0_c.y + x0.z*u0_c.z + x0.w*u0_c.w
                        + x1.x*u1_c.x + x1.y*u1_c.y + x1.z*u1_c.z + x1.w*u1_c.w;
                p = group_sum16(p);
                float wc = (r_c >= 0) ? 2.0f * w_c * p : 0.0f;
                acc0.x += w_c * x0.x - wc * u0_c.x;
                acc0.y += w_c * x0.y - wc * u0_c.y;
                acc0.z += w_c * x0.z - wc * u0_c.z;
                acc0.w += w_c * x0.w - wc * u0_c.w;
                acc1.x += w_c * x1.x - wc * u1_c.x;
                acc1.y += w_c * x1.y - wc * u1_c.y;
                acc1.z += w_c * x1.z - wc * u1_c.z;
                acc1.w += w_c * x1.w - wc * u1_c.w;
            }
        }
    }
    float Z = group_sum16(Zp);
    Z += __shfl_xor(Z, 16, 64);
    Z += __shfl_xor(Z, 32, 64);
#pragma unroll
    for (int m = 16; m < 64; m <<= 1) {
        acc0.x += __shfl_xor(acc0.x, m, 64);
        acc0.y += __shfl_xor(acc0.y, m, 64);
        acc0.z += __shfl_xor(acc0.z, m, 64);
        acc0.w += __shfl_xor(acc0.w, m, 64);
        acc1.x += __shfl_xor(acc1.x, m, 64);
        acc1.y += __shfl_xor(acc1.y, m, 64);
        acc1.z += __shfl_xor(acc1.z, m, 64);
        acc1.w += __shfl_xor(acc1.w, m, 64);
    }
    float invZ = (end > beg) ? (1.0f / Z) : 0.0f;
    float4 o0, o1;
    o0.x = tanh_fast(acc0.x * invZ); o0.y = tanh_fast(acc0.y * invZ);
    o0.z = tanh_fast(acc0.z * invZ); o0.w = tanh_fast(acc0.w * invZ);
    o1.x = tanh_fast(acc1.x * invZ); o1.y = tanh_fast(acc1.y * invZ);
    o1.z = tanh_fast(acc1.z * invZ); o1.w = tanh_fast(acc1.w * invZ);

    // per-node projections onto the 4 combined semantic weight vectors
    float pr[4];
#pragma unroll
    for (int k = 0; k < 4; ++k) {
        const float* wp = wcomb + k * D + 8 * l;
        float4 w0 = *(const float4*)wp;
        float4 w1 = *(const float4*)(wp + 4);
        float p = o0.x*w0.x + o0.y*w0.y + o0.z*w0.z + o0.w*w0.w
                + o1.x*w1.x + o1.y*w1.y + o1.z*w1.z + o1.w*w1.w;
        pr[k] = group_sum16(p);
    }
    if (lane == 0) {
        node_Z[n] = Z;
        *(float4*)(proj + 4 * (size_t)n) = make_float4(pr[0], pr[1], pr[2], pr[3]);
    }
    if (g == 0) {
        float* op = foutS + (size_t)n * OUT_COLS + 8 * l;
        *(float4*)op = o0;
        *(float4*)(op + 4) = o1;
        uint4 pk = make_uint4(pack_bf16x2(o0.x, o0.y), pack_bf16x2(o0.z, o0.w),
                              pack_bf16x2(o1.x, o1.y), pack_bf16x2(o1.z, o1.w));
        *((uint4*)(foutC + (size_t)n * D) + l) = pk;
    }
}

// --- semantic pass: per-edge weights from per-node projections; pipelined gathers ---
__global__ __launch_bounds__(256) void k_sem(
        const ushortT* __restrict__ featsC, // bf16 compact updated feats, stride D
        const float* __restrict__ seF,      // f32 copy of same feats (out0 slice)
        float* __restrict__ oput,           // out1 column slice, stride OUT_COLS
        const int* __restrict__ row_ptr, const int* __restrict__ srcv,
        const int* __restrict__ relv, const float* __restrict__ rval,
        const float* __restrict__ er, const float* __restrict__ node_Z,
        const float* __restrict__ proj,
        const float* __restrict__ attn_b, const float* __restrict__ gate_b) {
    int n    = (blockIdx.x * blockDim.x + threadIdx.x) >> 6;
    int lane = threadIdx.x & 63;
    int g = lane >> 4, l = lane & 15;
    if (n >= N_NODES) return;
    int beg = row_ptr[n], end = row_ptr[n + 1];

    float4 pn = *(const float4*)(proj + 4 * (size_t)n);
    float ca = pn.x + attn_b[0];
    float cg = pn.z + gate_b[0];
    float invZ = (end > beg) ? (1.0f / node_Z[n]) : 0.0f;

    float4 acc0 = make_float4(0.f, 0.f, 0.f, 0.f);
    float4 acc1 = make_float4(0.f, 0.f, 0.f, 0.f);
    float Zs = 0.f;

    for (int cs = beg; cs < end; cs += 64) {
        int cnt = min(64, end - cs);
        int my_s = 0; float my_wt = 0.f;
        if (lane < cnt) {
            int e = cs + lane;
            my_s = srcv[e];
            int rr = relv[e];
            bool pos = rval[e] > 0.0f;
            float sw = (pos ? er[rr] : 1.0f) * invZ;       // att_struct
            float4 ps = *(const float4*)(proj + 4 * (size_t)my_s);
            float as = fmaxf(sigmoid_fast(ca + ps.y), 1e-4f);
            float gt = sigmoid_fast(cg + ps.w);
            my_wt = __expf(gt * as + (1.0f - gt) * sw);    // logit in (0,1], exp-safe
            Zs += my_wt;
        }
        int nit = (cnt + 3) >> 2;
        int   s  = __shfl(my_s, g, 64);
        float wt = __shfl(my_wt, g, 64);
        uint4 xq = *((const uint4*)(featsC + (size_t)s * D) + l);
        for (int i = 0; i < nit; ++i) {
            float wt_c = wt; uint4 xq_c = xq;
            if (i + 1 < nit) {
                int sl2 = ((i + 1) << 2) | g;
                s  = __shfl(my_s, sl2, 64);
                wt = __shfl(my_wt, sl2, 64);
                xq = *((const uint4*)(featsC + (size_t)s * D) + l);
            }
            float4 x0, x1;
            bf16x8_to_f32(xq_c, x0, x1);
            acc0.x += wt_c * x0.x; acc0.y += wt_c * x0.y;
            acc0.z += wt_c * x0.z; acc0.w += wt_c * x0.w;
            acc1.x += wt_c * x1.x; acc1.y += wt_c * x1.y;
            acc1.z += wt_c * x1.z; acc1.w += wt_c * x1.w;
        }
    }
    Zs = group_sum16(Zs);
    Zs += __shfl_xor(Zs, 16, 64);
    Zs += __shfl_xor(Zs, 32, 64);
#pragma unroll
    for (int m = 16; m < 64; m <<= 1) {
        acc0.x += __shfl_xor(acc0.x, m, 64);
        acc0.y += __shfl_xor(acc0.y, m, 64);
        acc0.z += __shfl_xor(acc0.z, m, 64);
        acc0.w += __shfl_xor(acc0.w, m, 64);
        acc1.x += __shfl_xor(acc1.x, m, 64);
        acc1.y += __shfl_xor(acc1.y, m, 64);
        acc1.z += __shfl_xor(acc1.z, m, 64);
        acc1.w += __shfl_xor(acc1.w, m, 64);
    }
    if (g == 0) {
        float invZs = (end > beg) ? (1.0f / Zs) : 0.0f;
        float sc    = (end > beg) ? 1.0f : 0.0f;
        const float* sp = seF + (size_t)n * OUT_COLS + 8 * l;   // f32 se (accurate)
        float4 s0 = *(const float4*)sp;
        float4 s1 = *(const float4*)(sp + 4);
        float4 o0, o1;
        // out = tanh(se - (Σ wt·x)/Σ wt)
        o0.x = tanh_fast(sc * (s0.x - acc0.x * invZs));
        o0.y = tanh_fast(sc * (s0.y - acc0.y * invZs));
        o0.z = tanh_fast(sc * (s0.z - acc0.z * invZs));
        o0.w = tanh_fast(sc * (s0.w - acc0.w * invZs));
        o1.x = tanh_fast(sc * (s1.x - acc1.x * invZs));
        o1.y = tanh_fast(sc * (s1.y - acc1.y * invZs));
        o1.z = tanh_fast(sc * (s1.z - acc1.z * invZs));
        o1.w = tanh_fast(sc * (s1.w - acc1.w * invZs));
        float* op = oput + (size_t)n * OUT_COLS + 8 * l;
        *(float4*)op = o0;
        *(float4*)(op + 4) = o1;
    }
}

extern "C" void kernel_launch(void* const* d_in, const int* in_sizes, int n_in,
                              void* d_out, int out_size, void* d_ws, size_t ws_size,
                              hipStream_t stream) {
    const float* features = (const float*)d_in[0];
    const float* rel_emb  = (const float*)d_in[1];
    const int*   adj      = (const int*)d_in[2];   // [0:E]=dst (sorted), [E:2E]=src
    const int*   r_index  = (const int*)d_in[3];   // [0:E]=arange (identity), [E:2E]=rel
    const float* r_val    = (const float*)d_in[4];
    const float* attn_w   = (const float*)d_in[5];
    const float* attn_b   = (const float*)d_in[6];
    const float* gate_w   = (const float*)d_in[7];
    const float* gate_b   = (const float*)d_in[8];
    const float* attn_k   = (const float*)d_in[9]; // (2,128,1)

    float* out0 = (float*)d_out;                          // N x 384 (outs_c)
    float* out1 = out0 + (size_t)N_NODES * OUT_COLS;      // N x 384 (outs_s)

    // workspace carve-up (~41 MB)
    float* rel_norm = (float*)d_ws;                       // N_REL*D
    float* er0      = rel_norm + (size_t)N_REL * D;       // N_REL
    float* er1      = er0 + N_REL;                        // N_REL
    float* wcomb    = er1 + N_REL;                        // 4*D
    float* proj     = wcomb + 4 * D;                      // 4*N_NODES
    float* node_Z   = proj + 4 * (size_t)N_NODES;         // N_NODES
    int*   row_ptr  = (int*)(node_Z + N_NODES);           // N_NODES+1 (pad to +4)
    ushortT* fc0    = (ushortT*)(row_ptr + N_NODES + 4);  // N_NODES*D bf16
    ushortT* fc1    = fc0 + (size_t)N_NODES * D;          // N_NODES*D bf16
    ushortT* fc2    = fc1 + (size_t)N_NODES * D;          // N_NODES*D bf16

    const int* dstv = adj;
    const int* srcv = adj + N_EDGES;
    const int* relv = r_index + N_EDGES;

    k_setup<<<SETUP_BLOCKS, 256, 0, stream>>>(
        features, rel_emb, attn_k, attn_w, gate_w, dstv,
        out0, out1, fc0, rel_norm, er0, er1, wcomb, row_ptr);

    const ushortT* fcin[3] = {fc0, fc1, fc2};
    for (int l = 0; l < 2; ++l) {
        const float* er = l ? er1 : er0;
        k_struct<<<(N_NODES + 3) / 4, 256, 0, stream>>>(
            fcin[l], (ushortT*)fcin[l + 1], out0 + (size_t)(l + 1) * D,
            row_ptr, srcv, relv, r_val, er, rel_norm, wcomb, node_Z, proj);
        k_sem<<<(N_NODES + 3) / 4, 256, 0, stream>>>(
            fcin[l + 1], out0 + (size_t)(l + 1) * D, out1 + (size_t)(l + 1) * D,
            row_ptr, srcv, relv, r_val, er, node_Z, proj, attn_b, gate_b);
    }
}

// Round 7
// 360.569 us; speedup vs baseline: 1.2348x; 1.0453x over previous
//
#include <hip/hip_runtime.h>
#include <math.h>

#define N_NODES 50000
#define N_REL   1000
#define N_EDGES 600000
#define D       128
#define OUT_COLS 384   // 3*D concat output row stride

typedef unsigned short ushortT;

#define FEAT0_BLOCKS  ((N_NODES * (D / 4) + 255) / 256)   // 6250
#define RELN_BLOCKS   ((N_REL + 3) / 4)                   // 250
#define ROWPTR_BLOCKS ((N_NODES + 1 + 255) / 256)         // 196
#define SETUP_BLOCKS  (FEAT0_BLOCKS + RELN_BLOCKS + ROWPTR_BLOCKS + 1)

__device__ __forceinline__ float wave_reduce_sum64(float v) {
#pragma unroll
    for (int m = 1; m < 64; m <<= 1) v += __shfl_xor(v, m, 64);
    return v;
}

// --- DPP 16-lane sum: 4 VALU ops, result on all 16 lanes of each row ---
template <int CTRL>
__device__ __forceinline__ float dpp_add_(float v) {
    int t = __builtin_amdgcn_update_dpp(0, __float_as_int(v), CTRL, 0xf, 0xf, true);
    return v + __int_as_float(t);
}
__device__ __forceinline__ float group_sum16(float v) {
    v = dpp_add_<0xB1>(v);    // quad_perm [1,0,3,2]  (xor 1)
    v = dpp_add_<0x4E>(v);    // quad_perm [2,3,0,1]  (xor 2)
    v = dpp_add_<0x141>(v);   // row_half_mirror      (combine quads)
    v = dpp_add_<0x140>(v);   // row_mirror           (combine halves)
    return v;
}

__device__ __forceinline__ float tanh_fast(float x) {
    float cx = fminf(fmaxf(x, -20.0f), 20.0f);
    float e = __expf(2.0f * cx);
    return __fdividef(e - 1.0f, e + 1.0f);
}
__device__ __forceinline__ float sigmoid_fast(float x) {
    return __fdividef(1.0f, 1.0f + __expf(-x));
}

// --- bf16 helpers (gather buffers only; all accumulation stays f32) ---
__device__ __forceinline__ void bf16x8_to_f32(uint4 q, float4& a, float4& b) {
    a.x = __int_as_float((int)(q.x << 16));
    a.y = __int_as_float((int)(q.x & 0xffff0000u));
    a.z = __int_as_float((int)(q.y << 16));
    a.w = __int_as_float((int)(q.y & 0xffff0000u));
    b.x = __int_as_float((int)(q.z << 16));
    b.y = __int_as_float((int)(q.z & 0xffff0000u));
    b.z = __int_as_float((int)(q.w << 16));
    b.w = __int_as_float((int)(q.w & 0xffff0000u));
}
__device__ __forceinline__ unsigned pack_bf16x2(float lo, float hi) {
    unsigned a = __float_as_uint(lo), b = __float_as_uint(hi);
    a = (a + 0x7fffu + ((a >> 16) & 1u)) >> 16;          // RNE (inputs finite)
    b = (b + 0x7fffu + ((b >> 16) & 1u));
    return (a & 0xffffu) | (b & 0xffff0000u);
}

// --- fused setup: feats0 tanh (+bf16 compact copy) | relnorm+exp | rowptr | wcomb ---
__global__ __launch_bounds__(256) void k_setup(
        const float* __restrict__ features, const float* __restrict__ rel_emb,
        const float* __restrict__ attn_k, const float* __restrict__ attn_w,
        const float* __restrict__ gate_w, const int* __restrict__ dstv,
        float* __restrict__ out0, float* __restrict__ out1, ushortT* __restrict__ fc0,
        float* __restrict__ rel_norm, float* __restrict__ er0, float* __restrict__ er1,
        float* __restrict__ wcomb, int* __restrict__ row_ptr) {
    int bid = blockIdx.x, tid = threadIdx.x;
    if (bid < FEAT0_BLOCKS) {
        int i = bid * 256 + tid;
        if (i >= N_NODES * (D / 4)) return;
        int n = i >> 5, q = i & 31;
        float4 f = *(const float4*)(features + (size_t)n * D + 4 * q);
        f.x = tanh_fast(f.x); f.y = tanh_fast(f.y);
        f.z = tanh_fast(f.z); f.w = tanh_fast(f.w);
        *(float4*)(out0 + (size_t)n * OUT_COLS + 4 * q) = f;
        *(float4*)(out1 + (size_t)n * OUT_COLS + 4 * q) = f;
        uint2 p = make_uint2(pack_bf16x2(f.x, f.y), pack_bf16x2(f.z, f.w));
        *((uint2*)(fc0 + (size_t)n * D) + q) = p;
    } else if (bid < FEAT0_BLOCKS + RELN_BLOCKS) {
        int wid  = (bid - FEAT0_BLOCKS) * 4 + (tid >> 6);
        int lane = tid & 63;
        if (wid >= N_REL) return;
        float2 v = *(const float2*)(rel_emb + (size_t)wid * D + 2 * lane);
        float sq = wave_reduce_sum64(v.x * v.x + v.y * v.y);
        float inv = 1.0f / fmaxf(sqrtf(sq), 1e-12f);
        float2 u = make_float2(v.x * inv, v.y * inv);
        *(float2*)(rel_norm + (size_t)wid * D + 2 * lane) = u;
        float2 k0 = *(const float2*)(attn_k + 2 * lane);
        float2 k1 = *(const float2*)(attn_k + D + 2 * lane);
        float d0 = wave_reduce_sum64(u.x * k0.x + u.y * k0.y);
        float d1 = wave_reduce_sum64(u.x * k1.x + u.y * k1.y);
        if (lane == 0) { er0[wid] = __expf(d0); er1[wid] = __expf(d1); }
    } else if (bid < FEAT0_BLOCKS + RELN_BLOCKS + ROWPTR_BLOCKS) {
        int n = (bid - FEAT0_BLOCKS - RELN_BLOCKS) * 256 + tid;
        if (n > N_NODES) return;
        int lo = 0, hi = N_EDGES;
        while (lo < hi) {
            int mid = (lo + hi) >> 1;
            if (dstv[mid] < n) lo = mid + 1; else hi = mid;
        }
        row_ptr[n] = lo;
    } else {
        int j = tid;
        if (j >= D) return;
        wcomb[j]         = attn_w[j] + attn_w[2 * D + j];       // wA_dst
        wcomb[D + j]     = attn_w[D + j] - attn_w[2 * D + j];   // wA_src
        wcomb[2 * D + j] = gate_w[j] + gate_w[2 * D + j];       // wG_dst
        wcomb[3 * D + j] = gate_w[D + j] - gate_w[2 * D + j];   // wG_src
    }
}

// --- structural pass (layer 0): one wave per node, pipelined bf16 gathers ---
__global__ __launch_bounds__(256) void k_struct(
        const ushortT* __restrict__ finC,  // bf16 compact input feats, stride D
        ushortT* __restrict__ foutC,       // bf16 compact output feats, stride D
        float* __restrict__ foutS,         // out0 column slice (f32, stride OUT_COLS)
        const int* __restrict__ row_ptr, const int* __restrict__ srcv,
        const int* __restrict__ relv, const float* __restrict__ rval,
        const float* __restrict__ er,
        const float* __restrict__ rel_norm, const float* __restrict__ wcomb,
        float* __restrict__ node_Z, float* __restrict__ proj) {
    int n    = (blockIdx.x * blockDim.x + threadIdx.x) >> 6;
    int lane = threadIdx.x & 63;
    int g = lane >> 4, l = lane & 15;
    if (n >= N_NODES) return;
    int beg = row_ptr[n], end = row_ptr[n + 1];

    float4 acc0 = make_float4(0.f, 0.f, 0.f, 0.f);
    float4 acc1 = make_float4(0.f, 0.f, 0.f, 0.f);
    float Zp = 0.f;

    for (int cs = beg; cs < end; cs += 64) {
        int cnt = min(64, end - cs);
        int my_s = 0, my_r = -1; float my_w = 0.f;
        if (lane < cnt) {
            int e = cs + lane;
            my_s = srcv[e];
            int rr = relv[e];
            bool pos = rval[e] > 0.0f;   // r_val==0 -> tri_rel is zero vector
            my_r = pos ? rr : -1;
            my_w = pos ? er[rr] : 1.0f;
            Zp += my_w;
        }
        int nit = (cnt + 3) >> 2;
        int   s = __shfl(my_s, g, 64);
        int   r = __shfl(my_r, g, 64);
        float w = __shfl(my_w, g, 64);
        uint4 xq = *((const uint4*)(finC + (size_t)s * D) + l);
        int rr0 = r < 0 ? 0 : r;
        const float* up = rel_norm + (size_t)rr0 * D + 8 * l;
        float4 u0 = *(const float4*)up;
        float4 u1 = *(const float4*)(up + 4);
        for (int i = 0; i < nit; ++i) {
            int r_c = r; float w_c = w;
            uint4 xq_c = xq; float4 u0_c = u0, u1_c = u1;
            if (i + 1 < nit) {   // issue next iteration's gathers early
                int sl2 = ((i + 1) << 2) | g;
                s = __shfl(my_s, sl2, 64);
                r = __shfl(my_r, sl2, 64);
                w = __shfl(my_w, sl2, 64);
                xq = *((const uint4*)(finC + (size_t)s * D) + l);
                int rr2 = r < 0 ? 0 : r;
                const float* up2 = rel_norm + (size_t)rr2 * D + 8 * l;
                u0 = *(const float4*)up2;
                u1 = *(const float4*)(up2 + 4);
            }
            float4 x0, x1;
            bf16x8_to_f32(xq_c, x0, x1);
            float p = x0.x*u0_c.x + x0.y*u0_c.y + x0.z*u0_c.z + x0.w*u0_c.w
                    + x1.x*u1_c.x + x1.y*u1_c.y + x1.z*u1_c.z + x1.w*u1_c.w;
            p = group_sum16(p);
            float wc = (r_c >= 0) ? 2.0f * w_c * p : 0.0f;
            acc0.x += w_c * x0.x - wc * u0_c.x;
            acc0.y += w_c * x0.y - wc * u0_c.y;
            acc0.z += w_c * x0.z - wc * u0_c.z;
            acc0.w += w_c * x0.w - wc * u0_c.w;
            acc1.x += w_c * x1.x - wc * u1_c.x;
            acc1.y += w_c * x1.y - wc * u1_c.y;
            acc1.z += w_c * x1.z - wc * u1_c.z;
            acc1.w += w_c * x1.w - wc * u1_c.w;
        }
    }
    float Z = group_sum16(Zp);
    Z += __shfl_xor(Z, 16, 64);
    Z += __shfl_xor(Z, 32, 64);
#pragma unroll
    for (int m = 16; m < 64; m <<= 1) {
        acc0.x += __shfl_xor(acc0.x, m, 64);
        acc0.y += __shfl_xor(acc0.y, m, 64);
        acc0.z += __shfl_xor(acc0.z, m, 64);
        acc0.w += __shfl_xor(acc0.w, m, 64);
        acc1.x += __shfl_xor(acc1.x, m, 64);
        acc1.y += __shfl_xor(acc1.y, m, 64);
        acc1.z += __shfl_xor(acc1.z, m, 64);
        acc1.w += __shfl_xor(acc1.w, m, 64);
    }
    float invZ = (end > beg) ? (1.0f / Z) : 0.0f;
    float4 o0, o1;
    o0.x = tanh_fast(acc0.x * invZ); o0.y = tanh_fast(acc0.y * invZ);
    o0.z = tanh_fast(acc0.z * invZ); o0.w = tanh_fast(acc0.w * invZ);
    o1.x = tanh_fast(acc1.x * invZ); o1.y = tanh_fast(acc1.y * invZ);
    o1.z = tanh_fast(acc1.z * invZ); o1.w = tanh_fast(acc1.w * invZ);

    float pr[4];
#pragma unroll
    for (int k = 0; k < 4; ++k) {
        const float* wp = wcomb + k * D + 8 * l;
        float4 w0 = *(const float4*)wp;
        float4 w1 = *(const float4*)(wp + 4);
        float p = o0.x*w0.x + o0.y*w0.y + o0.z*w0.z + o0.w*w0.w
                + o1.x*w1.x + o1.y*w1.y + o1.z*w1.z + o1.w*w1.w;
        pr[k] = group_sum16(p);
    }
    if (lane == 0) {
        node_Z[n] = Z;
        *(float4*)(proj + 4 * (size_t)n) = make_float4(pr[0], pr[1], pr[2], pr[3]);
    }
    if (g == 0) {
        float* op = foutS + (size_t)n * OUT_COLS + 8 * l;
        *(float4*)op = o0;
        *(float4*)(op + 4) = o1;
        uint4 pk = make_uint4(pack_bf16x2(o0.x, o0.y), pack_bf16x2(o0.z, o0.w),
                              pack_bf16x2(o1.x, o1.y), pack_bf16x2(o1.z, o1.w));
        *((uint4*)(foutC + (size_t)n * D) + l) = pk;
    }
}

// --- fused pass: sem(layer l) + struct(layer l+1), single gather of level-l+1 feats ---
__global__ __launch_bounds__(256) void k_fused(
        const ushortT* __restrict__ finC,  // bf16 level-l+1 feats, stride D
        const float* __restrict__ seF,     // f32 same feats (out0 slice l+1)
        ushortT* __restrict__ foutC,       // bf16 level-l+2 feats out
        float* __restrict__ foutS,         // out0 slice l+2 (f32)
        float* __restrict__ oputSem,       // out1 slice l+1 (f32)
        const int* __restrict__ row_ptr, const int* __restrict__ srcv,
        const int* __restrict__ relv, const float* __restrict__ rval,
        const float* __restrict__ er_sem,  // layer-l structural exp table
        const float* __restrict__ er_st,   // layer-l+1 structural exp table
        const float* __restrict__ rel_norm, const float* __restrict__ wcomb,
        const float* __restrict__ node_Z0, const float* __restrict__ proj0,
        float* __restrict__ node_Z1, float* __restrict__ proj1,
        const float* __restrict__ attn_b, const float* __restrict__ gate_b) {
    int n    = (blockIdx.x * blockDim.x + threadIdx.x) >> 6;
    int lane = threadIdx.x & 63;
    int g = lane >> 4, l = lane & 15;
    if (n >= N_NODES) return;
    int beg = row_ptr[n], end = row_ptr[n + 1];

    float4 pn = *(const float4*)(proj0 + 4 * (size_t)n);
    float ca = pn.x + attn_b[0];
    float cg = pn.z + gate_b[0];
    float invZ0 = (end > beg) ? (1.0f / node_Z0[n]) : 0.0f;

    float4 st0 = make_float4(0.f, 0.f, 0.f, 0.f);   // struct accumulators
    float4 st1 = make_float4(0.f, 0.f, 0.f, 0.f);
    float4 sm0 = make_float4(0.f, 0.f, 0.f, 0.f);   // sem accumulators
    float4 sm1 = make_float4(0.f, 0.f, 0.f, 0.f);
    float Zp = 0.f, Zs = 0.f;

    for (int cs = beg; cs < end; cs += 64) {
        int cnt = min(64, end - cs);
        int my_s = 0, my_r = -1; float my_w = 0.f, my_wt = 0.f;
        if (lane < cnt) {
            int e = cs + lane;
            my_s = srcv[e];
            int rr = relv[e];
            bool pos = rval[e] > 0.0f;
            my_r = pos ? rr : -1;
            my_w = pos ? er_st[rr] : 1.0f;               // struct weight (layer l+1)
            float sw = (pos ? er_sem[rr] : 1.0f) * invZ0; // att_struct (layer l)
            float4 ps = *(const float4*)(proj0 + 4 * (size_t)my_s);
            float as = fmaxf(sigmoid_fast(ca + ps.y), 1e-4f);
            float gt = sigmoid_fast(cg + ps.w);
            my_wt = __expf(gt * as + (1.0f - gt) * sw);   // sem weight, exp-safe
            Zp += my_w; Zs += my_wt;
        }
        int nit = (cnt + 3) >> 2;
        int   s  = __shfl(my_s, g, 64);
        int   r  = __shfl(my_r, g, 64);
        float w  = __shfl(my_w, g, 64);
        float wt = __shfl(my_wt, g, 64);
        uint4 xq = *((const uint4*)(finC + (size_t)s * D) + l);
        int rr0 = r < 0 ? 0 : r;
        const float* up = rel_norm + (size_t)rr0 * D + 8 * l;
        float4 u0 = *(const float4*)up;
        float4 u1 = *(const float4*)(up + 4);
        for (int i = 0; i < nit; ++i) {
            int r_c = r; float w_c = w, wt_c = wt;
            uint4 xq_c = xq; float4 u0_c = u0, u1_c = u1;
            if (i + 1 < nit) {
                int sl2 = ((i + 1) << 2) | g;
                s  = __shfl(my_s, sl2, 64);
                r  = __shfl(my_r, sl2, 64);
                w  = __shfl(my_w, sl2, 64);
                wt = __shfl(my_wt, sl2, 64);
                xq = *((const uint4*)(finC + (size_t)s * D) + l);
                int rr2 = r < 0 ? 0 : r;
                const float* up2 = rel_norm + (size_t)rr2 * D + 8 * l;
                u0 = *(const float4*)up2;
                u1 = *(const float4*)(up2 + 4);
            }
            float4 x0, x1;
            bf16x8_to_f32(xq_c, x0, x1);
            float p = x0.x*u0_c.x + x0.y*u0_c.y + x0.z*u0_c.z + x0.w*u0_c.w
                    + x1.x*u1_c.x + x1.y*u1_c.y + x1.z*u1_c.z + x1.w*u1_c.w;
            p = group_sum16(p);
            float wc = (r_c >= 0) ? 2.0f * w_c * p : 0.0f;
            st0.x += w_c * x0.x - wc * u0_c.x;
            st0.y += w_c * x0.y - wc * u0_c.y;
            st0.z += w_c * x0.z - wc * u0_c.z;
            st0.w += w_c * x0.w - wc * u0_c.w;
            st1.x += w_c * x1.x - wc * u1_c.x;
            st1.y += w_c * x1.y - wc * u1_c.y;
            st1.z += w_c * x1.z - wc * u1_c.z;
            st1.w += w_c * x1.w - wc * u1_c.w;
            sm0.x += wt_c * x0.x; sm0.y += wt_c * x0.y;
            sm0.z += wt_c * x0.z; sm0.w += wt_c * x0.w;
            sm1.x += wt_c * x1.x; sm1.y += wt_c * x1.y;
            sm1.z += wt_c * x1.z; sm1.w += wt_c * x1.w;
        }
    }
    float Z = group_sum16(Zp);
    Z += __shfl_xor(Z, 16, 64);
    Z += __shfl_xor(Z, 32, 64);
    float ZsT = group_sum16(Zs);
    ZsT += __shfl_xor(ZsT, 16, 64);
    ZsT += __shfl_xor(ZsT, 32, 64);
#pragma unroll
    for (int m = 16; m < 64; m <<= 1) {
        st0.x += __shfl_xor(st0.x, m, 64); st0.y += __shfl_xor(st0.y, m, 64);
        st0.z += __shfl_xor(st0.z, m, 64); st0.w += __shfl_xor(st0.w, m, 64);
        st1.x += __shfl_xor(st1.x, m, 64); st1.y += __shfl_xor(st1.y, m, 64);
        st1.z += __shfl_xor(st1.z, m, 64); st1.w += __shfl_xor(st1.w, m, 64);
        sm0.x += __shfl_xor(sm0.x, m, 64); sm0.y += __shfl_xor(sm0.y, m, 64);
        sm0.z += __shfl_xor(sm0.z, m, 64); sm0.w += __shfl_xor(sm0.w, m, 64);
        sm1.x += __shfl_xor(sm1.x, m, 64); sm1.y += __shfl_xor(sm1.y, m, 64);
        sm1.z += __shfl_xor(sm1.z, m, 64); sm1.w += __shfl_xor(sm1.w, m, 64);
    }
    float invZ = (end > beg) ? (1.0f / Z) : 0.0f;
    float4 o0, o1;
    o0.x = tanh_fast(st0.x * invZ); o0.y = tanh_fast(st0.y * invZ);
    o0.z = tanh_fast(st0.z * invZ); o0.w = tanh_fast(st0.w * invZ);
    o1.x = tanh_fast(st1.x * invZ); o1.y = tanh_fast(st1.y * invZ);
    o1.z = tanh_fast(st1.z * invZ); o1.w = tanh_fast(st1.w * invZ);

    float pr[4];
#pragma unroll
    for (int k = 0; k < 4; ++k) {
        const float* wp = wcomb + k * D + 8 * l;
        float4 w0 = *(const float4*)wp;
        float4 w1 = *(const float4*)(wp + 4);
        float p = o0.x*w0.x + o0.y*w0.y + o0.z*w0.z + o0.w*w0.w
                + o1.x*w1.x + o1.y*w1.y + o1.z*w1.z + o1.w*w1.w;
        pr[k] = group_sum16(p);
    }
    if (lane == 0) {
        node_Z1[n] = Z;
        *(float4*)(proj1 + 4 * (size_t)n) = make_float4(pr[0], pr[1], pr[2], pr[3]);
    }
    if (g == 0) {
        // struct outputs (level l+2)
        float* op = foutS + (size_t)n * OUT_COLS + 8 * l;
        *(float4*)op = o0;
        *(float4*)(op + 4) = o1;
        uint4 pk = make_uint4(pack_bf16x2(o0.x, o0.y), pack_bf16x2(o0.z, o0.w),
                              pack_bf16x2(o1.x, o1.y), pack_bf16x2(o1.z, o1.w));
        *((uint4*)(foutC + (size_t)n * D) + l) = pk;
        // sem output (layer l): tanh(se - Σwt·x/Σwt)
        float invZs = (end > beg) ? (1.0f / ZsT) : 0.0f;
        float sc    = (end > beg) ? 1.0f : 0.0f;
        const float* sp = seF + (size_t)n * OUT_COLS + 8 * l;
        float4 s0 = *(const float4*)sp;
        float4 s1 = *(const float4*)(sp + 4);
        float4 q0, q1;
        q0.x = tanh_fast(sc * (s0.x - sm0.x * invZs));
        q0.y = tanh_fast(sc * (s0.y - sm0.y * invZs));
        q0.z = tanh_fast(sc * (s0.z - sm0.z * invZs));
        q0.w = tanh_fast(sc * (s0.w - sm0.w * invZs));
        q1.x = tanh_fast(sc * (s1.x - sm1.x * invZs));
        q1.y = tanh_fast(sc * (s1.y - sm1.y * invZs));
        q1.z = tanh_fast(sc * (s1.z - sm1.z * invZs));
        q1.w = tanh_fast(sc * (s1.w - sm1.w * invZs));
        float* oq = oputSem + (size_t)n * OUT_COLS + 8 * l;
        *(float4*)oq = q0;
        *(float4*)(oq + 4) = q1;
    }
}

// --- semantic pass (layer 1): per-edge weights from projections; pipelined gathers ---
__global__ __launch_bounds__(256) void k_sem(
        const ushortT* __restrict__ featsC, // bf16 compact updated feats, stride D
        const float* __restrict__ seF,      // f32 copy of same feats (out0 slice)
        float* __restrict__ oput,           // out1 column slice, stride OUT_COLS
        const int* __restrict__ row_ptr, const int* __restrict__ srcv,
        const int* __restrict__ relv, const float* __restrict__ rval,
        const float* __restrict__ er, const float* __restrict__ node_Z,
        const float* __restrict__ proj,
        const float* __restrict__ attn_b, const float* __restrict__ gate_b) {
    int n    = (blockIdx.x * blockDim.x + threadIdx.x) >> 6;
    int lane = threadIdx.x & 63;
    int g = lane >> 4, l = lane & 15;
    if (n >= N_NODES) return;
    int beg = row_ptr[n], end = row_ptr[n + 1];

    float4 pn = *(const float4*)(proj + 4 * (size_t)n);
    float ca = pn.x + attn_b[0];
    float cg = pn.z + gate_b[0];
    float invZ = (end > beg) ? (1.0f / node_Z[n]) : 0.0f;

    float4 acc0 = make_float4(0.f, 0.f, 0.f, 0.f);
    float4 acc1 = make_float4(0.f, 0.f, 0.f, 0.f);
    float Zs = 0.f;

    for (int cs = beg; cs < end; cs += 64) {
        int cnt = min(64, end - cs);
        int my_s = 0; float my_wt = 0.f;
        if (lane < cnt) {
            int e = cs + lane;
            my_s = srcv[e];
            int rr = relv[e];
            bool pos = rval[e] > 0.0f;
            float sw = (pos ? er[rr] : 1.0f) * invZ;
            float4 ps = *(const float4*)(proj + 4 * (size_t)my_s);
            float as = fmaxf(sigmoid_fast(ca + ps.y), 1e-4f);
            float gt = sigmoid_fast(cg + ps.w);
            my_wt = __expf(gt * as + (1.0f - gt) * sw);
            Zs += my_wt;
        }
        int nit = (cnt + 3) >> 2;
        int   s  = __shfl(my_s, g, 64);
        float wt = __shfl(my_wt, g, 64);
        uint4 xq = *((const uint4*)(featsC + (size_t)s * D) + l);
        for (int i = 0; i < nit; ++i) {
            float wt_c = wt; uint4 xq_c = xq;
            if (i + 1 < nit) {
                int sl2 = ((i + 1) << 2) | g;
                s  = __shfl(my_s, sl2, 64);
                wt = __shfl(my_wt, sl2, 64);
                xq = *((const uint4*)(featsC + (size_t)s * D) + l);
            }
            float4 x0, x1;
            bf16x8_to_f32(xq_c, x0, x1);
            acc0.x += wt_c * x0.x; acc0.y += wt_c * x0.y;
            acc0.z += wt_c * x0.z; acc0.w += wt_c * x0.w;
            acc1.x += wt_c * x1.x; acc1.y += wt_c * x1.y;
            acc1.z += wt_c * x1.z; acc1.w += wt_c * x1.w;
        }
    }
    Zs = group_sum16(Zs);
    Zs += __shfl_xor(Zs, 16, 64);
    Zs += __shfl_xor(Zs, 32, 64);
#pragma unroll
    for (int m = 16; m < 64; m <<= 1) {
        acc0.x += __shfl_xor(acc0.x, m, 64);
        acc0.y += __shfl_xor(acc0.y, m, 64);
        acc0.z += __shfl_xor(acc0.z, m, 64);
        acc0.w += __shfl_xor(acc0.w, m, 64);
        acc1.x += __shfl_xor(acc1.x, m, 64);
        acc1.y += __shfl_xor(acc1.y, m, 64);
        acc1.z += __shfl_xor(acc1.z, m, 64);
        acc1.w += __shfl_xor(acc1.w, m, 64);
    }
    if (g == 0) {
        float invZs = (end > beg) ? (1.0f / Zs) : 0.0f;
        float sc    = (end > beg) ? 1.0f : 0.0f;
        const float* sp = seF + (size_t)n * OUT_COLS + 8 * l;
        float4 s0 = *(const float4*)sp;
        float4 s1 = *(const float4*)(sp + 4);
        float4 o0, o1;
        o0.x = tanh_fast(sc * (s0.x - acc0.x * invZs));
        o0.y = tanh_fast(sc * (s0.y - acc0.y * invZs));
        o0.z = tanh_fast(sc * (s0.z - acc0.z * invZs));
        o0.w = tanh_fast(sc * (s0.w - acc0.w * invZs));
        o1.x = tanh_fast(sc * (s1.x - acc1.x * invZs));
        o1.y = tanh_fast(sc * (s1.y - acc1.y * invZs));
        o1.z = tanh_fast(sc * (s1.z - acc1.z * invZs));
        o1.w = tanh_fast(sc * (s1.w - acc1.w * invZs));
        float* op = oput + (size_t)n * OUT_COLS + 8 * l;
        *(float4*)op = o0;
        *(float4*)(op + 4) = o1;
    }
}

extern "C" void kernel_launch(void* const* d_in, const int* in_sizes, int n_in,
                              void* d_out, int out_size, void* d_ws, size_t ws_size,
                              hipStream_t stream) {
    const float* features = (const float*)d_in[0];
    const float* rel_emb  = (const float*)d_in[1];
    const int*   adj      = (const int*)d_in[2];   // [0:E]=dst (sorted), [E:2E]=src
    const int*   r_index  = (const int*)d_in[3];   // [0:E]=arange (identity), [E:2E]=rel
    const float* r_val    = (const float*)d_in[4];
    const float* attn_w   = (const float*)d_in[5];
    const float* attn_b   = (const float*)d_in[6];
    const float* gate_w   = (const float*)d_in[7];
    const float* gate_b   = (const float*)d_in[8];
    const float* attn_k   = (const float*)d_in[9]; // (2,128,1)

    float* out0 = (float*)d_out;                          // N x 384 (outs_c)
    float* out1 = out0 + (size_t)N_NODES * OUT_COLS;      // N x 384 (outs_s)

    // workspace carve-up (~42 MB)
    float* rel_norm = (float*)d_ws;                       // N_REL*D
    float* er0      = rel_norm + (size_t)N_REL * D;       // N_REL
    float* er1      = er0 + N_REL;                        // N_REL
    float* wcomb    = er1 + N_REL;                        // 4*D
    float* proj0    = wcomb + 4 * D;                      // 4*N_NODES
    float* proj1    = proj0 + 4 * (size_t)N_NODES;        // 4*N_NODES
    float* node_Z0  = proj1 + 4 * (size_t)N_NODES;        // N_NODES
    float* node_Z1  = node_Z0 + N_NODES;                  // N_NODES
    int*   row_ptr  = (int*)(node_Z1 + N_NODES);          // N_NODES+1 (pad to +4)
    ushortT* fc0    = (ushortT*)(row_ptr + N_NODES + 4);  // N_NODES*D bf16
    ushortT* fc1    = fc0 + (size_t)N_NODES * D;          // N_NODES*D bf16
    ushortT* fc2    = fc1 + (size_t)N_NODES * D;          // N_NODES*D bf16

    const int* dstv = adj;
    const int* srcv = adj + N_EDGES;
    const int* relv = r_index + N_EDGES;

    k_setup<<<SETUP_BLOCKS, 256, 0, stream>>>(
        features, rel_emb, attn_k, attn_w, gate_w, dstv,
        out0, out1, fc0, rel_norm, er0, er1, wcomb, row_ptr);

    // layer 0 structural: gather level-0, produce level-1 (+ proj0/node_Z0)
    k_struct<<<(N_NODES + 3) / 4, 256, 0, stream>>>(
        fc0, fc1, out0 + (size_t)1 * D,
        row_ptr, srcv, relv, r_val, er0, rel_norm, wcomb, node_Z0, proj0);

    // fused: sem layer-0 + struct layer-1 — single gather of level-1 feats
    k_fused<<<(N_NODES + 3) / 4, 256, 0, stream>>>(
        fc1, out0 + (size_t)1 * D, fc2, out0 + (size_t)2 * D, out1 + (size_t)1 * D,
        row_ptr, srcv, relv, r_val, er0, er1, rel_norm, wcomb,
        node_Z0, proj0, node_Z1, proj1, attn_b, gate_b);

    // sem layer-1: gather level-2 feats
    k_sem<<<(N_NODES + 3) / 4, 256, 0, stream>>>(
        fc2, out0 + (size_t)2 * D, out1 + (size_t)2 * D,
        row_ptr, srcv, relv, r_val, er1, node_Z1, proj1, attn_b, gate_b);
}